// Round 3
// baseline (92.668 us; speedup 1.0000x reference)
//
#include <hip/hip_runtime.h>
#include <math.h>

// Problem constants (B, NA, NO, D, C, T) = (2048, 64, 64, 128, 64, 3)
#define NB 2048
#define NNODES 129
#define ND 128
#define NC 64

// ws float layout:
//  [0]              : mask-dtype flag (int): 0=int32, 1=bytes(bool/int8), 2=float32
//  [16 .. 16+1152)  : u[j*3+i][d]  (9 x 128)   u = W[j] @ a1[i]
//  [1168 .. +384)   : v2[i][d]     (3 x 128)   v2 = W[i] @ a2[i]

__device__ __forceinline__ bool mask_at(const void* m, int flag, int idx) {
  if (flag == 1) return ((const unsigned char*)m)[idx] != 0;
  if (flag == 2) return ((const float*)m)[idx] != 0.0f;
  return ((const int*)m)[idx] != 0;
}

__global__ void hetgat_precomp(const float* __restrict__ W, const float* __restrict__ a,
                               const void* __restrict__ mask, float* __restrict__ ws) {
  int gidx = blockIdx.x * 256 + threadIdx.x;
  if (blockIdx.x == 6) {
    if (threadIdx.x == 0) {
      const unsigned char* mb = (const unsigned char*)mask;
      const unsigned int* mw = (const unsigned int*)mask;
      bool bytes01 = true, words01 = true, wordsF = true;
      for (int i = 0; i < 256; ++i) { if (mb[i] > 1) bytes01 = false; }
      for (int i = 0; i < 64; ++i) {
        unsigned int w = mw[i];
        if (w != 0u && w != 1u) words01 = false;
        if (w != 0u && w != 0x3F800000u) wordsF = false;
      }
      int flag;
      if (words01) flag = 0;
      else if (bytes01) flag = 1;
      else if (wordsF) flag = 2;
      else flag = 1;
      ((int*)ws)[0] = flag;
    }
    return;
  }
  if (gidx < 1152) {                // u[j*3+i][d] = sum_c W[j,d,c] * a1[i,c]
    int ji = gidx >> 7, d = gidx & 127;
    int j = ji / 3, i = ji - 3 * j;
    const float4* Wp = (const float4*)(W + j * 8192 + d * 64);
    const float4* ap = (const float4*)(a + i * 128);
    float s = 0.f;
#pragma unroll
    for (int c = 0; c < 16; ++c) {
      float4 w4 = Wp[c], a4 = ap[c];
      s += w4.x * a4.x + w4.y * a4.y + w4.z * a4.z + w4.w * a4.w;
    }
    ws[16 + gidx] = s;
  } else if (gidx < 1536) {         // v2[i][d] = sum_c W[i,d,c] * a2[i,c]
    int rel = gidx - 1152;
    int i = rel >> 7, d = rel & 127;
    const float4* Wp = (const float4*)(W + i * 8192 + d * 64);
    const float4* ap = (const float4*)(a + i * 128 + 64);
    float s = 0.f;
#pragma unroll
    for (int c = 0; c < 16; ++c) {
      float4 w4 = Wp[c], a4 = ap[c];
      s += w4.x * a4.x + w4.y * a4.y + w4.z * a4.z + w4.w * a4.w;
    }
    ws[1168 + rel] = s;
  }
}

__global__ __launch_bounds__(256, 8) void hetgat_main(
    const float* __restrict__ h, const float* __restrict__ W,
    const void* __restrict__ mask, const float* __restrict__ ws,
    float* __restrict__ out) {
  __shared__ float es[12];
  __shared__ float ea[192], eo[192];
  __shared__ float wa[192], wo[192];
  __shared__ float msf[4];
  __shared__ float gpart[4 * 384];
  __shared__ float gl[384];
  __shared__ float red[256];

  const int b = blockIdx.x;
  const int tid = threadIdx.x;
  const int wv = tid >> 6, ln = tid & 63;
  const int flag = ((const int*)ws)[0];
  const float* __restrict__ hb = h + (size_t)b * NNODES * ND;

  // ---- pass 1: attention logits, straight from global (no staging) ----
  if (wv < 3) {
    const float4* hra = (const float4*)(hb + (1 + ln) * ND);   // ally row per lane
    const float4* hro = (const float4*)(hb + (65 + ln) * ND);  // opp row per lane
    const float4* vv  = (const float4*)(ws + 1168 + wv * ND);  // v2[type], L2-hot
    float sa = 0.f, so = 0.f;
#pragma unroll 4
    for (int c = 0; c < 32; ++c) {
      float4 v = vv[c];
      float4 x = hra[c];
      float4 y = hro[c];
      sa += x.x * v.x + x.y * v.y + x.z * v.z + x.w * v.w;
      so += y.x * v.x + y.y * v.y + y.z * v.z + y.w * v.w;
    }
    int mbase = (wv * NB + b) * NNODES;
    ea[wv * 64 + ln] = mask_at(mask, flag, mbase + 1 + ln)  ? -INFINITY : sa;
    eo[wv * 64 + ln] = mask_at(mask, flag, mbase + 65 + ln) ? -INFINITY : so;
  } else {
    if (ln < 9) {                      // e_self[j*3+i] = h_self . u[j,i]
      const float4* uu = (const float4*)(ws + 16 + (ln << 7));
      const float4* hs = (const float4*)(hb);  // row 0
      float s = 0.f;
#pragma unroll 4
      for (int c = 0; c < 32; ++c) {
        float4 u4 = uu[c], x = hs[c];
        s += x.x * u4.x + x.y * u4.y + x.z * u4.z + x.w * u4.w;
      }
      es[ln] = s;
    } else if (ln < 12) {
      int t = ln - 9;
      msf[t] = mask_at(mask, flag, (t * NB + b) * NNODES) ? 1.f : 0.f;
    }
  }
  __syncthreads();

  // ---- pass 2: collapsed softmax (wave0 = ally, wave1 = opp) ----
  if (wv < 2) {
    float* e = (wv == 0) ? ea : eo;
    float* w = (wv == 0) ? wa : wo;
    float ms[3], S[3];
#pragma unroll
    for (int i = 0; i < 3; ++i) {
      float e0 = es[i], e1 = es[3 + i], e2 = es[6 + i];
      float m = fmaxf(fmaxf(e0, e1), e2);
      ms[i] = m;
      S[i] = expf(e0 - m) + expf(e1 - m) + expf(e2 - m);
    }
    float v0 = e[ln], v1 = e[64 + ln], v2v = e[128 + ln];
    float c0 = v0 + ms[0], c1 = v1 + ms[1], c2 = v2v + ms[2];
    float mx = fmaxf(fmaxf(c0, c1), c2);
    for (int off = 32; off; off >>= 1) mx = fmaxf(mx, __shfl_xor(mx, off));
    float t0 = 0.f, t1 = 0.f, t2 = 0.f;
    if (mx != -INFINITY) {
      t0 = (v0  == -INFINITY) ? 0.f : S[0] * expf(c0 - mx);
      t1 = (v1  == -INFINITY) ? 0.f : S[1] * expf(c1 - mx);
      t2 = (v2v == -INFINITY) ? 0.f : S[2] * expf(c2 - mx);
    }
    float z = t0 + t1 + t2;
    for (int off = 32; off; off >>= 1) z += __shfl_xor(z, off);
    float inv = (z > 0.f) ? 1.f / z : 0.f;
    w[ln] = t0 * inv; w[64 + ln] = t1 * inv; w[128 + ln] = t2 * inv;
  }
  __syncthreads();

  // ---- pass 3: 4-wave row-partitioned partial weighted sums ----
  // wave w handles rows 1+32w .. 32+32w  (waves 0-1: ally n in [0,64); waves 2-3: opp)
  {
    const float* wsel = (wv < 2) ? wa : wo;
    const int nb0 = (wv & 1) * 32;
    const float2* hp = (const float2*)(hb + (1 + 32 * wv) * ND) + ln;  // d-pair per lane
    float a00 = 0.f, a01 = 0.f, a10 = 0.f, a11 = 0.f, a20 = 0.f, a21 = 0.f;
#pragma unroll 4
    for (int r = 0; r < 32; ++r) {
      float2 f = hp[(size_t)r * 64];          // coalesced 512B per wave
      float w0 = wsel[nb0 + r];
      float w1 = wsel[64 + nb0 + r];
      float w2 = wsel[128 + nb0 + r];
      a00 += w0 * f.x; a01 += w0 * f.y;
      a10 += w1 * f.x; a11 += w1 * f.y;
      a20 += w2 * f.x; a21 += w2 * f.y;
    }
    float* gp = gpart + wv * 384;
    *(float2*)(gp + 0 * 128 + 2 * ln) = make_float2(a00, a01);
    *(float2*)(gp + 1 * 128 + 2 * ln) = make_float2(a10, a11);
    *(float2*)(gp + 2 * 128 + 2 * ln) = make_float2(a20, a21);
  }
  __syncthreads();

  // ---- pass 4: reduce partials + masked self contribution ----
  if (tid < 192) {
    const int t = wv;                  // 0..2
    float2 s0 = *(float2*)(gpart + 0 * 384 + t * 128 + 2 * ln);
    float2 s1 = *(float2*)(gpart + 1 * 384 + t * 128 + 2 * ln);
    float2 s2 = *(float2*)(gpart + 2 * 384 + t * 128 + 2 * ln);
    float2 s3 = *(float2*)(gpart + 3 * 384 + t * 128 + 2 * ln);
    float2 hs = *(const float2*)(hb + 2 * ln);   // self row, L1/L2-hot
    float m = msf[t];
    *(float2*)(gl + t * 128 + 2 * ln) =
        make_float2(s0.x + s1.x + s2.x + s3.x + m * hs.x,
                    s0.y + s1.y + s2.y + s3.y + m * hs.y);
  }
  __syncthreads();

  // ---- pass 5: epilogue out[b,c] = elu( sum_t g[t] @ W[t][:,c] ) ----
  {
    int q = tid >> 6, c = tid & 63;
    float acc = 0.f;
#pragma unroll
    for (int t = 0; t < 3; ++t) {
      const float* gp = gl + t * ND;
      const float* Wp = W + t * 8192;
#pragma unroll 4
      for (int dd = 32 * q; dd < 32 * q + 32; ++dd) {
        acc += gp[dd] * Wp[dd * 64 + c];
      }
    }
    red[q * 64 + c] = acc;
  }
  __syncthreads();
  if (tid < 64) {
    float x = red[tid] + red[64 + tid] + red[128 + tid] + red[192 + tid];
    out[(size_t)b * NC + tid] = (x > 0.f) ? x : expm1f(x);
  }
}

extern "C" void kernel_launch(void* const* d_in, const int* in_sizes, int n_in,
                              void* d_out, int out_size, void* d_ws, size_t ws_size,
                              hipStream_t stream) {
  (void)in_sizes; (void)n_in; (void)out_size; (void)ws_size;
  const float* h   = (const float*)d_in[0];
  const float* W   = (const float*)d_in[1];
  const float* a   = (const float*)d_in[2];
  const void* mask = d_in[3];
  float* ws  = (float*)d_ws;
  float* out = (float*)d_out;

  hetgat_precomp<<<dim3(7), dim3(256), 0, stream>>>(W, a, mask, ws);
  hetgat_main<<<dim3(NB), dim3(256), 0, stream>>>(h, W, mask, ws, out);
}

// Round 4
// 64.304 us; speedup vs baseline: 1.4411x; 1.4411x over previous
//
#include <hip/hip_runtime.h>
#include <math.h>

// Problem constants (B, NA, NO, D, C, T) = (2048, 64, 64, 128, 64, 3)
#define NB 2048
#define NNODES 129
#define ND 128
#define NC 64

typedef unsigned int u32;
typedef short bf16x8 __attribute__((ext_vector_type(8)));
typedef float f32x4 __attribute__((ext_vector_type(4)));

// ws layout: [0] mask-dtype flag (int); u32[16..16+1024) = bf16 B-panel in
// MFMA fragment order: panel[q], q = s*256 + l*4 + rp; element pair
// (r=2rp, 2rp+1): B[k][col], k = s*32 + (l>>4)*8 + r, col = l&15.
// cols 0..2 = v2[i] (W[i]@a2[i]); cols 3..11 = u[j*3+i] (W[j]@a1[i]); 12..15 = 0.
#define WS_PANEL 16

__device__ __forceinline__ bool mask_at(const void* m, int flag, int idx) {
  if (flag == 1) return ((const unsigned char*)m)[idx] != 0;
  if (flag == 2) return ((const float*)m)[idx] != 0.0f;
  return ((const int*)m)[idx] != 0;
}

__device__ __forceinline__ u32 pack2bf(float a, float b) {
  u32 ua, ub;
  __builtin_memcpy(&ua, &a, 4);
  __builtin_memcpy(&ub, &b, 4);
  // RNE round to bf16
  u32 ra = (ua + 0x7fff + ((ua >> 16) & 1)) >> 16;
  u32 rb = (ub + 0x7fff + ((ub >> 16) & 1)) >> 16;
  return (ra & 0xffffu) | (rb << 16);
}
__device__ __forceinline__ float2 unpack2bf(u32 w) {
  float lo = __builtin_bit_cast(float, w << 16);
  float hi = __builtin_bit_cast(float, w & 0xffff0000u);
  return make_float2(lo, hi);
}

__global__ void hetgat_precomp(const float* __restrict__ W, const float* __restrict__ a,
                               const void* __restrict__ mask, float* __restrict__ ws) {
  int tid = threadIdx.x;
  if (tid == 0) {
    const unsigned char* mb = (const unsigned char*)mask;
    const unsigned int* mw = (const unsigned int*)mask;
    bool bytes01 = true, words01 = true, wordsF = true;
    for (int i = 0; i < 256; ++i) { if (mb[i] > 1) bytes01 = false; }
    for (int i = 0; i < 64; ++i) {
      unsigned int w = mw[i];
      if (w != 0u && w != 1u) words01 = false;
      if (w != 0u && w != 0x3F800000u) wordsF = false;
    }
    int flag;
    if (words01) flag = 0;
    else if (bytes01) flag = 1;
    else if (wordsF) flag = 2;
    else flag = 1;
    ((int*)ws)[0] = flag;
  }
  u32* panel = (u32*)ws + WS_PANEL;
  for (int p = 0; p < 4; ++p) {
    int q = p * 256 + tid;
    int s = q >> 8, rem = q & 255, l = rem >> 2, rp = rem & 3;
    int col = l & 15;
    float v01[2];
#pragma unroll
    for (int e = 0; e < 2; ++e) {
      int r = rp * 2 + e;
      int k = s * 32 + (l >> 4) * 8 + r;
      float acc = 0.f;
      if (col < 12) {
        int j = (col < 3) ? col : (col - 3) / 3;
        int i = (col < 3) ? col : (col - 3) % 3;
        int aoff = (col < 3) ? (i * 128 + 64) : (i * 128);
        const float4* Wp = (const float4*)(W + j * 8192 + k * 64);
        const float4* ap = (const float4*)(a + aoff);
#pragma unroll
        for (int c = 0; c < 16; ++c) {
          float4 w4 = Wp[c], a4 = ap[c];
          acc += w4.x * a4.x + w4.y * a4.y + w4.z * a4.z + w4.w * a4.w;
        }
      }
      v01[e] = acc;
    }
    panel[q] = pack2bf(v01[0], v01[1]);
  }
}

// LDS float-offsets. hl: 129 rows x 64 u32 (bf16x2), 16B-chunk XOR swizzle by (row&7).
#define OFF_WA   8256   // 192
#define OFF_WO   8448   // 192
#define OFF_MSF  8640   // 4
#define OFF_ERA  8644   // 192  (union: gl[384] after pass2)
#define OFF_ERO  8836   // 192
#define OFF_ES   9028   // 12   (union: red[256] after pass3)
#define OFF_GL   8644
#define OFF_RED  9028
#define LDS_FLOATS 9284  // 37136 B -> 4 blocks/CU; also covers MFMA tile-8 reads (<= 9216)

__global__ __launch_bounds__(256, 4) void hetgat_main(
    const float* __restrict__ h, const float* __restrict__ W,
    const void* __restrict__ mask, const float* __restrict__ ws,
    float* __restrict__ out) {
  __shared__ float lds[LDS_FLOATS];
  u32* hlu   = (u32*)lds;
  float* wa  = lds + OFF_WA;
  float* wo  = lds + OFF_WO;
  float* msf = lds + OFF_MSF;
  float* era = lds + OFF_ERA;
  float* ero = lds + OFF_ERO;
  float* esl = lds + OFF_ES;
  float* gl  = lds + OFF_GL;
  float* red = lds + OFF_RED;

  const int b = blockIdx.x;
  const int tid = threadIdx.x;
  const int wv = tid >> 6, ln = tid & 63;
  const int flag = ((const int*)ws)[0];

  // ---- entry: prefetch masks (regs) + B-panel fragments (regs) ----
  bool mreg0 = false, mreg1 = false, mreg2 = false;
  float msreg = 0.f;
  if (wv == 0) {
    int base = b * NNODES + 1 + ln;
    mreg0 = mask_at(mask, flag, 0 * NB * NNODES + base);
    mreg1 = mask_at(mask, flag, 1 * NB * NNODES + base);
    mreg2 = mask_at(mask, flag, 2 * NB * NNODES + base);
  } else if (wv == 1) {
    int base = b * NNODES + 65 + ln;
    mreg0 = mask_at(mask, flag, 0 * NB * NNODES + base);
    mreg1 = mask_at(mask, flag, 1 * NB * NNODES + base);
    mreg2 = mask_at(mask, flag, 2 * NB * NNODES + base);
  } else if (wv == 2 && ln < 3) {
    msreg = mask_at(mask, flag, (ln * NB + b) * NNODES) ? 1.f : 0.f;
  }
  uint4 bfr[4];
  {
    const u32* panel = (const u32*)ws + WS_PANEL;
#pragma unroll
    for (int s = 0; s < 4; ++s)
      bfr[s] = *(const uint4*)(panel + (s * 64 + ln) * 4);
  }

  // ---- pass 0: stage h[b] (129x128 f32 -> bf16) into LDS, swizzled ----
  const float4* h4 = (const float4*)(h + (size_t)b * NNODES * ND);
  for (int idx = tid; idx < NNODES * 32; idx += 256) {
    int r = idx >> 5, c4f = idx & 31;        // c4f: float4 index (8 bf16 = half 16B-chunk)
    int chunk = c4f >> 1, half = c4f & 1;
    float4 v = h4[idx];
    uint2 p;
    p.x = pack2bf(v.x, v.y);
    p.y = pack2bf(v.z, v.w);
    int swz = chunk ^ (r & 7);
    *((uint2*)(hlu + r * 64 + swz * 4 + half * 2)) = p;
  }
  __syncthreads();

  // ---- pass 1: all 129x12 logits via MFMA 16x16x32 bf16 (9 row-tiles / 4 waves) ----
  for (int t = wv; t < 9; t += 4) {
    f32x4 acc = {0.f, 0.f, 0.f, 0.f};
#pragma unroll
    for (int s = 0; s < 4; ++s) {
      int row = t * 16 + (ln & 15);
      int c4 = s * 4 + (ln >> 4);
      const uint4* ap = (const uint4*)(hlu + row * 64 + ((c4 ^ (row & 7)) << 2));
      bf16x8 a8 = __builtin_bit_cast(bf16x8, *ap);
      bf16x8 b8 = __builtin_bit_cast(bf16x8, bfr[s]);
      acc = __builtin_amdgcn_mfma_f32_16x16x32_bf16(a8, b8, acc, 0, 0, 0);
    }
    int c = ln & 15;
    int rbase = t * 16 + ((ln >> 4) << 2);
#pragma unroll
    for (int j = 0; j < 4; ++j) {
      int row = rbase + j;
      float val = acc[j];
      if (c < 3) {
        if (row >= 1 && row < 65) era[c * 64 + row - 1] = val;
        else if (row >= 65 && row < 129) ero[c * 64 + row - 65] = val;
      } else if (c < 12 && row == 0) {
        esl[c - 3] = val;                    // es[j*3+i], index = c-3
      }
    }
  }
  if (wv == 2 && ln < 3) msf[ln] = msreg;
  __syncthreads();

  // ---- pass 2: collapsed softmax (wave0 = ally, wave1 = opp) ----
  if (wv < 2) {
    const float* e = (wv == 0) ? era : ero;
    float* w = (wv == 0) ? wa : wo;
    float ms[3], S[3];
#pragma unroll
    for (int i = 0; i < 3; ++i) {
      float e0 = esl[i], e1 = esl[3 + i], e2 = esl[6 + i];
      float m = fmaxf(fmaxf(e0, e1), e2);
      ms[i] = m;
      S[i] = __expf(e0 - m) + __expf(e1 - m) + __expf(e2 - m);
    }
    float v0 = mreg0 ? -INFINITY : e[ln];
    float v1 = mreg1 ? -INFINITY : e[64 + ln];
    float v2v = mreg2 ? -INFINITY : e[128 + ln];
    float c0 = v0 + ms[0], c1 = v1 + ms[1], c2 = v2v + ms[2];
    float mx = fmaxf(fmaxf(c0, c1), c2);
    for (int off = 32; off; off >>= 1) mx = fmaxf(mx, __shfl_xor(mx, off));
    float t0 = 0.f, t1 = 0.f, t2 = 0.f;
    if (mx != -INFINITY) {
      t0 = mreg0 ? 0.f : S[0] * __expf(c0 - mx);
      t1 = mreg1 ? 0.f : S[1] * __expf(c1 - mx);
      t2 = mreg2 ? 0.f : S[2] * __expf(c2 - mx);
    }
    float z = t0 + t1 + t2;
    for (int off = 32; off; off >>= 1) z += __shfl_xor(z, off);
    float inv = (z > 0.f) ? 1.f / z : 0.f;
    w[ln] = t0 * inv; w[64 + ln] = t1 * inv; w[128 + ln] = t2 * inv;
  }
  __syncthreads();

  // ---- pass 3: g[t][d] = msf_t*h_self[d] + sum_n w[t,n]*h_node[n,d]  (wave = type) ----
  if (wv < 3) {
    const int l2 = ln;                       // owns d-pair (2*l2, 2*l2+1)
    float2 fs = unpack2bf(hlu[l2]);          // row 0: swizzle is identity
    float m = msf[wv];
    float a0 = m * fs.x, a1 = m * fs.y;
    const float* wap = wa + wv * 64;
    const float* wop = wo + wv * 64;
    const int chh = l2 >> 2, sub = l2 & 3;
#pragma unroll 8
    for (int n = 0; n < 64; ++n) {
      int row = 1 + n;
      float2 f = unpack2bf(hlu[row * 64 + ((chh ^ (row & 7)) << 2) + sub]);
      float wgt = wap[n];
      a0 += wgt * f.x; a1 += wgt * f.y;
    }
#pragma unroll 8
    for (int n = 0; n < 64; ++n) {
      int row = 65 + n;
      float2 f = unpack2bf(hlu[row * 64 + ((chh ^ (row & 7)) << 2) + sub]);
      float wgt = wop[n];
      a0 += wgt * f.x; a1 += wgt * f.y;
    }
    gl[wv * ND + 2 * l2] = a0;
    gl[wv * ND + 2 * l2 + 1] = a1;
  }
  __syncthreads();

  // ---- pass 4: epilogue out[b,c] = elu( sum_t g[t] @ W[t][:,c] ) ----
  {
    int q = tid >> 6, c = tid & 63;
    float acc = 0.f;
#pragma unroll
    for (int t = 0; t < 3; ++t) {
      const float* gp = gl + t * ND;
      const float* Wp = W + t * 8192;
#pragma unroll 4
      for (int dd = 32 * q; dd < 32 * q + 32; ++dd) {
        acc += gp[dd] * Wp[dd * 64 + c];
      }
    }
    red[q * 64 + c] = acc;
  }
  __syncthreads();
  if (tid < 64) {
    float x = red[tid] + red[64 + tid] + red[128 + tid] + red[192 + tid];
    out[(size_t)b * NC + tid] = (x > 0.f) ? x : expm1f(x);
  }
}

extern "C" void kernel_launch(void* const* d_in, const int* in_sizes, int n_in,
                              void* d_out, int out_size, void* d_ws, size_t ws_size,
                              hipStream_t stream) {
  (void)in_sizes; (void)n_in; (void)out_size; (void)ws_size;
  const float* h   = (const float*)d_in[0];
  const float* W   = (const float*)d_in[1];
  const float* a   = (const float*)d_in[2];
  const void* mask = d_in[3];
  float* ws  = (float*)d_ws;
  float* out = (float*)d_out;

  hetgat_precomp<<<dim3(1), dim3(256), 0, stream>>>(W, a, mask, ws);
  hetgat_main<<<dim3(NB), dim3(256), 0, stream>>>(h, W, mask, ws, out);
}

// Round 5
// 50.208 us; speedup vs baseline: 1.8457x; 1.2808x over previous
//
#include <hip/hip_runtime.h>
#include <math.h>

// Problem constants (B, NA, NO, D, C, T) = (2048, 64, 64, 128, 64, 3)
#define NB 2048
#define NNODES 129
#define ND 128
#define NC 64

typedef unsigned int u32;

// ws float layout:
//  [0]              : mask-dtype flag (int): 0=int32, 1=bytes(bool/int8), 2=float32
//  [16 .. 16+1152)  : u[j*3+i][d]  (9 x 128)   u = W[j] @ a1[i]
//  [1168 .. +384)   : v2[i][d]     (3 x 128)   v2 = W[i] @ a2[i]

__device__ __forceinline__ bool mask_at(const void* m, int flag, int idx) {
  if (flag == 1) return ((const unsigned char*)m)[idx] != 0;
  if (flag == 2) return ((const float*)m)[idx] != 0.0f;
  return ((const int*)m)[idx] != 0;
}

__device__ __forceinline__ u32 pack2bf(float a, float b) {
  u32 ua, ub;
  __builtin_memcpy(&ua, &a, 4);
  __builtin_memcpy(&ub, &b, 4);
  u32 ra = (ua + 0x7fff + ((ua >> 16) & 1)) >> 16;   // RNE
  u32 rb = (ub + 0x7fff + ((ub >> 16) & 1)) >> 16;
  return (ra & 0xffffu) | (rb << 16);
}
__device__ __forceinline__ float2 unpack2bf(u32 w) {
  float lo = __builtin_bit_cast(float, w << 16);
  float hi = __builtin_bit_cast(float, w & 0xffff0000u);
  return make_float2(lo, hi);
}

__global__ void hetgat_precomp(const float* __restrict__ W, const float* __restrict__ a,
                               const void* __restrict__ mask, float* __restrict__ ws) {
  int gidx = blockIdx.x * 256 + threadIdx.x;
  if (blockIdx.x == 6) {
    if (threadIdx.x == 0) {
      const unsigned char* mb = (const unsigned char*)mask;
      const unsigned int* mw = (const unsigned int*)mask;
      bool bytes01 = true, words01 = true, wordsF = true;
      for (int i = 0; i < 256; ++i) { if (mb[i] > 1) bytes01 = false; }
      for (int i = 0; i < 64; ++i) {
        unsigned int w = mw[i];
        if (w != 0u && w != 1u) words01 = false;
        if (w != 0u && w != 0x3F800000u) wordsF = false;
      }
      int flag;
      if (words01) flag = 0;
      else if (bytes01) flag = 1;
      else if (wordsF) flag = 2;
      else flag = 1;
      ((int*)ws)[0] = flag;
    }
    return;
  }
  if (gidx < 1152) {                // u[j*3+i][d] = sum_c W[j,d,c] * a1[i,c]
    int ji = gidx >> 7, d = gidx & 127;
    int j = ji / 3, i = ji - 3 * j;
    const float4* Wp = (const float4*)(W + j * 8192 + d * 64);
    const float4* ap = (const float4*)(a + i * 128);
    float s = 0.f;
#pragma unroll
    for (int c = 0; c < 16; ++c) {
      float4 w4 = Wp[c], a4 = ap[c];
      s += w4.x * a4.x + w4.y * a4.y + w4.z * a4.z + w4.w * a4.w;
    }
    ws[16 + gidx] = s;
  } else if (gidx < 1536) {         // v2[i][d] = sum_c W[i,d,c] * a2[i,c]
    int rel = gidx - 1152;
    int i = rel >> 7, d = rel & 127;
    const float4* Wp = (const float4*)(W + i * 8192 + d * 64);
    const float4* ap = (const float4*)(a + i * 128 + 64);
    float s = 0.f;
#pragma unroll
    for (int c = 0; c < 16; ++c) {
      float4 w4 = Wp[c], a4 = ap[c];
      s += w4.x * a4.x + w4.y * a4.y + w4.z * a4.z + w4.w * a4.w;
    }
    ws[1168 + rel] = s;
  }
}

// LDS float-offsets. hl: 129 rows x 64 u32 (bf16x2), 16B-chunk XOR swizzle by (row&7).
#define OFF_WA   8256   // 192
#define OFF_WO   8448   // 192
#define OFF_MSF  8640   // 4
#define OFF_ERA  8644   // 192  (union: gl[384] after pass2)
#define OFF_ERO  8836   // 192
#define OFF_ES   9028   // 12   (union: red[256] after pass3)
#define OFF_GL   8644
#define OFF_RED  9028
#define LDS_FLOATS 9284  // 37,136 B -> 4 blocks/CU

__global__ __launch_bounds__(256, 4) void hetgat_main(
    const float* __restrict__ h, const float* __restrict__ W,
    const void* __restrict__ mask, const float* __restrict__ ws,
    float* __restrict__ out) {
  __shared__ float lds[LDS_FLOATS];
  u32* hlu   = (u32*)lds;
  float* wa  = lds + OFF_WA;
  float* wo  = lds + OFF_WO;
  float* msf = lds + OFF_MSF;
  float* era = lds + OFF_ERA;
  float* ero = lds + OFF_ERO;
  float* esl = lds + OFF_ES;
  float* gl  = lds + OFF_GL;
  float* red = lds + OFF_RED;

  const int b = blockIdx.x;
  const int tid = threadIdx.x;
  const int wv = tid >> 6, ln = tid & 63;
  const int flag = ((const int*)ws)[0];

  // ---- entry: prefetch masks into registers (hidden under staging) ----
  bool mreg0 = false, mreg1 = false, mreg2 = false;
  float msreg = 0.f;
  if (wv == 0) {
    int base = b * NNODES + 1 + ln;
    mreg0 = mask_at(mask, flag, 0 * NB * NNODES + base);
    mreg1 = mask_at(mask, flag, 1 * NB * NNODES + base);
    mreg2 = mask_at(mask, flag, 2 * NB * NNODES + base);
  } else if (wv == 1) {
    int base = b * NNODES + 65 + ln;
    mreg0 = mask_at(mask, flag, 0 * NB * NNODES + base);
    mreg1 = mask_at(mask, flag, 1 * NB * NNODES + base);
    mreg2 = mask_at(mask, flag, 2 * NB * NNODES + base);
  } else if (wv == 2 && ln < 3) {
    msreg = mask_at(mask, flag, (ln * NB + b) * NNODES) ? 1.f : 0.f;
  }

  // ---- pass 0: stage h[b] (129x128 f32 -> bf16) into LDS, swizzled ----
  const float4* h4 = (const float4*)(h + (size_t)b * NNODES * ND);
  for (int idx = tid; idx < NNODES * 32; idx += 256) {
    int r = idx >> 5, c4f = idx & 31;        // c4f: float4 index (8B = half 16B-chunk)
    int chunk = c4f >> 1, half = c4f & 1;
    float4 v = h4[idx];
    uint2 p;
    p.x = pack2bf(v.x, v.y);
    p.y = pack2bf(v.z, v.w);
    int swz = chunk ^ (r & 7);
    *((uint2*)(hlu + r * 64 + swz * 4 + half * 2)) = p;
  }
  if (wv == 2 && ln < 3) msf[ln] = msreg;
  __syncthreads();

  // ---- pass 1: attention logits (scalar dots from swizzled bf16 LDS) ----
  if (wv < 3) {
    const int i = wv;                 // type index
    const int ra = 1 + ln;            // ally row
    const int ro = 65 + ln;           // opp row
    const u32* hraB = hlu + ra * 64;
    const u32* hroB = hlu + ro * 64;
    const float4* vv = (const float4*)(ws + 1168 + i * ND);  // wave-uniform -> s_load
    const int sax = ra & 7, sox = ro & 7;
    float sa = 0.f, so = 0.f;
#pragma unroll 4
    for (int ch = 0; ch < 16; ++ch) {
      uint4 xa = *(const uint4*)(hraB + ((ch ^ sax) << 2));
      uint4 xo = *(const uint4*)(hroB + ((ch ^ sox) << 2));
      float4 v0 = vv[2 * ch], v1 = vv[2 * ch + 1];
      float2 a0 = unpack2bf(xa.x), a1 = unpack2bf(xa.y), a2 = unpack2bf(xa.z), a3 = unpack2bf(xa.w);
      float2 o0 = unpack2bf(xo.x), o1 = unpack2bf(xo.y), o2 = unpack2bf(xo.z), o3 = unpack2bf(xo.w);
      sa += a0.x * v0.x + a0.y * v0.y + a1.x * v0.z + a1.y * v0.w
          + a2.x * v1.x + a2.y * v1.y + a3.x * v1.z + a3.y * v1.w;
      so += o0.x * v0.x + o0.y * v0.y + o1.x * v0.z + o1.y * v0.w
          + o2.x * v1.x + o2.y * v1.y + o3.x * v1.z + o3.y * v1.w;
    }
    era[i * 64 + ln] = sa;
    ero[i * 64 + ln] = so;
  } else {
    if (ln < 9) {                     // e_self[j*3+i] = h_self . u[j,i]
      const float4* uu = (const float4*)(ws + 16 + (ln << 7));
      const uint4* hs = (const uint4*)(hlu);   // row 0: swizzle identity, broadcast
      float s = 0.f;
#pragma unroll 4
      for (int ch = 0; ch < 16; ++ch) {
        uint4 x = hs[ch];
        float4 u0 = uu[2 * ch], u1 = uu[2 * ch + 1];
        float2 f0 = unpack2bf(x.x), f1 = unpack2bf(x.y), f2 = unpack2bf(x.z), f3 = unpack2bf(x.w);
        s += f0.x * u0.x + f0.y * u0.y + f1.x * u0.z + f1.y * u0.w
           + f2.x * u1.x + f2.y * u1.y + f3.x * u1.z + f3.y * u1.w;
      }
      esl[ln] = s;
    }
  }
  __syncthreads();

  // ---- pass 2: collapsed softmax (wave0 = ally, wave1 = opp) ----
  if (wv < 2) {
    const float* e = (wv == 0) ? era : ero;
    float* w = (wv == 0) ? wa : wo;
    float ms[3], S[3];
#pragma unroll
    for (int i = 0; i < 3; ++i) {
      float e0 = esl[i], e1 = esl[3 + i], e2 = esl[6 + i];
      float m = fmaxf(fmaxf(e0, e1), e2);
      ms[i] = m;
      S[i] = __expf(e0 - m) + __expf(e1 - m) + __expf(e2 - m);
    }
    float v0  = mreg0 ? -INFINITY : e[ln];
    float v1  = mreg1 ? -INFINITY : e[64 + ln];
    float v2v = mreg2 ? -INFINITY : e[128 + ln];
    float c0 = v0 + ms[0], c1 = v1 + ms[1], c2 = v2v + ms[2];
    float mx = fmaxf(fmaxf(c0, c1), c2);
    for (int off = 32; off; off >>= 1) mx = fmaxf(mx, __shfl_xor(mx, off));
    float t0 = 0.f, t1 = 0.f, t2 = 0.f;
    if (mx != -INFINITY) {
      t0 = mreg0 ? 0.f : S[0] * __expf(c0 - mx);
      t1 = mreg1 ? 0.f : S[1] * __expf(c1 - mx);
      t2 = mreg2 ? 0.f : S[2] * __expf(c2 - mx);
    }
    float z = t0 + t1 + t2;
    for (int off = 32; off; off >>= 1) z += __shfl_xor(z, off);
    float inv = (z > 0.f) ? 1.f / z : 0.f;
    w[ln] = t0 * inv; w[64 + ln] = t1 * inv; w[128 + ln] = t2 * inv;
  }
  __syncthreads();

  // ---- pass 3: g[t][d] = msf_t*h_self[d] + sum_n w[t,n]*h_node[n,d]  (wave = type) ----
  if (wv < 3) {
    const int l2 = ln;                       // owns d-pair (2*l2, 2*l2+1)
    float2 fs = unpack2bf(hlu[l2]);          // row 0: swizzle identity
    float m = msf[wv];
    float a0 = m * fs.x, a1 = m * fs.y;
    const float* wap = wa + wv * 64;
    const float* wop = wo + wv * 64;
    const int chh = l2 >> 2, sub = l2 & 3;
#pragma unroll 8
    for (int n = 0; n < 64; ++n) {
      int row = 1 + n;
      float2 f = unpack2bf(hlu[row * 64 + ((chh ^ (row & 7)) << 2) + sub]);
      float wgt = wap[n];
      a0 += wgt * f.x; a1 += wgt * f.y;
    }
#pragma unroll 8
    for (int n = 0; n < 64; ++n) {
      int row = 65 + n;
      float2 f = unpack2bf(hlu[row * 64 + ((chh ^ (row & 7)) << 2) + sub]);
      float wgt = wop[n];
      a0 += wgt * f.x; a1 += wgt * f.y;
    }
    gl[wv * ND + 2 * l2] = a0;
    gl[wv * ND + 2 * l2 + 1] = a1;
  }
  __syncthreads();

  // ---- pass 4: epilogue out[b,c] = elu( sum_t g[t] @ W[t][:,c] ) ----
  {
    int q = tid >> 6, c = tid & 63;
    float acc = 0.f;
#pragma unroll
    for (int t = 0; t < 3; ++t) {
      const float* gp = gl + t * ND;
      const float* Wp = W + t * 8192 + c;
#pragma unroll 16
      for (int dd = 32 * q; dd < 32 * q + 32; ++dd) {
        acc += gp[dd] * Wp[dd * 64];
      }
    }
    red[(tid >> 6) * 64 + (tid & 63)] = acc;
  }
  __syncthreads();
  if (tid < 64) {
    float x = red[tid] + red[64 + tid] + red[128 + tid] + red[192 + tid];
    out[(size_t)b * NC + tid] = (x > 0.f) ? x : expm1f(x);
  }
}

extern "C" void kernel_launch(void* const* d_in, const int* in_sizes, int n_in,
                              void* d_out, int out_size, void* d_ws, size_t ws_size,
                              hipStream_t stream) {
  (void)in_sizes; (void)n_in; (void)out_size; (void)ws_size;
  const float* h   = (const float*)d_in[0];
  const float* W   = (const float*)d_in[1];
  const float* a   = (const float*)d_in[2];
  const void* mask = d_in[3];
  float* ws  = (float*)d_ws;
  float* out = (float*)d_out;

  hetgat_precomp<<<dim3(7), dim3(256), 0, stream>>>(W, a, mask, ws);
  hetgat_main<<<dim3(NB), dim3(256), 0, stream>>>(h, W, mask, ws, out);
}